// Round 5
// baseline (1080.333 us; speedup 1.0000x reference)
//
#include <hip/hip_runtime.h>

// ---------------- problem constants (fixed by setup_inputs) ----------------
constexpr int kH  = 48;
constexpr int kW  = 160;
constexpr int kP  = 7680;   // kH*kW
constexpr int kC  = 128;
constexpr int kNB = 64;
constexpr int kNH = 8;
constexpr int kNL = 6;

// workspace layout (in floats) — total ~260 MB (R4-proven extent)
constexpr long long OFF_F1T = 0;
constexpr long long OFF_F2T = 983040;
constexpr long long OFF_WTS = 1966080;
// per-layer folded weight block (element offsets, elements are 4 B).
// std matrices (SA/Q/V/O): u16 idx = (c>>3)*1024 + (d&1)*512 + (d>>1)*8 + (c&7)
//   -> per j-chunk: [2 d-parity][64 lane][4 u32], lane stride 16 B
// WKU: u16 idx = h*2048 + q*512 + (c>>1)*8 + (op&3)*2 + (o&1), q=(c&1)*2+(op>>2)
constexpr int WSA2 = 0;
constexpr int WQ2  = 8192;
constexpr int WKU  = 16384;
constexpr int WV2  = 24576;
constexpr int WO2  = 32768;
constexpr int BSA  = 40960;    // f32 [128]
constexpr int BQ   = 41088;
constexpr int BK   = 41216;
constexpr int BV   = 41344;
constexpr int WTS_STRIDE = 41472;
// f16x2 scores volume: u32 idx = pix*4096 + bin*64 + pair   (126 MB, coalesced)
constexpr long long OFF_F2H  = OFF_WTS + 6LL * WTS_STRIDE;          // 2214912
// f16x2 bin-pair volume: u32 idx = pix*4096 + bp*128 + c    (126 MB)
constexpr long long OFF_F2HT = OFF_F2H + 31457280LL;

// d_out regions (floats)
constexpr long long OUT_ATT  = 0;         // (1,48,160,64)
constexpr long long OUT_MASK = 491520;    // (64,1,48,160)
constexpr long long OUT_LC   = 983040;    // (1,48,160)
constexpr long long OUT_SSIM = 990720;    // (1,64,48,160)

// ---------------- helpers ----------------
typedef _Float16 h2v __attribute__((ext_vector_type(2)));
typedef __fp16 p2v __attribute__((ext_vector_type(2)));
typedef float f2v __attribute__((ext_vector_type(2)));
typedef __fp16 h8 __attribute__((ext_vector_type(8)));
typedef float fx16 __attribute__((ext_vector_type(16)));
union U32H2 { unsigned u; h2v h; };
union U32P2 { unsigned u; p2v h; };

__device__ __forceinline__ float fdot2(unsigned a, unsigned b, float c) {
  U32H2 ua; ua.u = a; U32H2 ub; ub.u = b;
  return __builtin_amdgcn_fdot2(ua.h, ub.h, c, false);
}
__device__ __forceinline__ unsigned pkrtz(float a, float b) {
  U32P2 t; t.h = __builtin_amdgcn_cvt_pkrtz(a, b); return t.u;
}
__device__ __forceinline__ f2v h2f(unsigned u) {
  U32P2 t; t.u = u; f2v r; r.x = (float)t.h.x; r.y = (float)t.h.y; return r;
}
__device__ __forceinline__ unsigned short f2h(float x) {
  U32P2 t; t.h = __builtin_amdgcn_cvt_pkrtz(x, 0.f); return (unsigned short)(t.u & 0xffffu);
}
// compiler-order pin for wave-internal LDS producer->consumer (HW LDS is in-order per wave)
__device__ __forceinline__ void wb() {
  __asm__ __volatile__("" ::: "memory");
  __builtin_amdgcn_wave_barrier();
  __asm__ __volatile__("" ::: "memory");
}

// async global->LDS: 16 B per lane; LDS dest = uniform base + lane*16
typedef __attribute__((address_space(1))) const void gvoid_t;
typedef __attribute__((address_space(3))) void svoid_t;
__device__ __forceinline__ void gl_lds16(const unsigned* g, unsigned* s) {
  __builtin_amdgcn_global_load_lds((gvoid_t*)g, (svoid_t*)s, 16, 0, 0);
}

// ---------------- kernel 1: NCHW -> [pix][c] transpose, LDS-tiled ----------------
__global__ __launch_bounds__(256) void k_transpose(const float* __restrict__ feat1,
                                                   const float* __restrict__ feat2,
                                                   float* __restrict__ f1t,
                                                   float* __restrict__ f2t) {
  __shared__ float t1[32][33], t2[32][33];
  const int p0 = blockIdx.x * 32, c0 = blockIdx.y * 32;
  const int r = threadIdx.x >> 5, col = threadIdx.x & 31;
#pragma unroll
  for (int rr = r; rr < 32; rr += 8) {
    t1[rr][col] = feat1[(c0 + rr) * kP + p0 + col];
    t2[rr][col] = feat2[(c0 + rr) * kP + p0 + col];
  }
  __syncthreads();
#pragma unroll
  for (int rr = r; rr < 32; rr += 8) {
    f1t[(p0 + rr) * kC + c0 + col] = t1[col][rr];
    f2t[(p0 + rr) * kC + c0 + col] = t2[col][rr];
  }
}

// ---------------- kernel 2: fold LN gamma/beta + combine SA Wo@Wv, pack f16 ----------------
__device__ __forceinline__ float redsum128(float v, float* red2) {
#pragma unroll
  for (int off = 32; off > 0; off >>= 1) v += __shfl_xor(v, off);
  int t = threadIdx.x;
  if ((t & 63) == 0) red2[t >> 6] = v;
  __syncthreads();
  float r = red2[0] + red2[1];
  __syncthreads();
  return r;
}

__global__ __launch_bounds__(128) void k_fold(
    const float* __restrict__ saw_, const float* __restrict__ sab_,
    const float* __restrict__ sow_, const float* __restrict__ sob_,
    const float* __restrict__ slg_, const float* __restrict__ slb_,
    const float* __restrict__ caw_, const float* __restrict__ cab_,
    const float* __restrict__ clg_, const float* __restrict__ clb_,
    const float* __restrict__ cow_, float* __restrict__ wts) {
  int i = blockIdx.x >> 7, d = blockIdx.x & 127, c = threadIdx.x;
  const float* saw = saw_ + (long long)i * 384 * kC;
  const float* sab = sab_ + i * 384;
  const float* sow = sow_ + i * kC * kC;
  const float* sob = sob_ + i * kC;
  const float* slg = slg_ + i * kC;
  const float* slb = slb_ + i * kC;
  const float* caw = caw_ + (long long)i * 384 * kC;
  const float* cab = cab_ + i * 384;
  const float* clg = clg_ + i * kC;
  const float* clb = clb_ + i * kC;
  const float* cow = cow_ + i * kC * kC;
  float* WL = wts + (long long)i * WTS_STRIDE;
  __shared__ float red2[2];

  // std matrix u16 index for (c,d): per-j [2 parity][64 lane][8 u16]
  int jstd = (c >> 3) * 1024 + (d & 1) * 512 + (d >> 1) * 8 + (c & 7);

  // ---- SA: Wsa_pre = Wo_sa @ Wv_sa, fold ln gamma/beta ----
  float acc = 0.f;
  for (int m = 0; m < kC; m++) acc += sow[d * kC + m] * saw[(256 + m) * kC + c];
  float t1 = redsum128(acc * slb[c] + sow[d * kC + c] * sab[256 + c], red2);
  if (c == 0) WL[BSA + d] = t1 + sob[d];
  ((unsigned short*)(WL + WSA2))[jstd] = f2h(acc * slg[c]);

  // ---- Q (x0.25 fold) ----
  float wq = caw[d * kC + c];
  float t2 = redsum128(wq * clb[c], red2);
  if (c == 0) WL[BQ + d] = 0.25f * (t2 + cab[d]);
  ((unsigned short*)(WL + WQ2))[jstd] = f2h(0.25f * wq * clg[c]);

  // ---- K -> WKU [h][4 q][64 lane][4 u32] ----
  float wk = caw[(kC + d) * kC + c];
  float t3 = redsum128(wk * clb[c], red2);
  if (c == 0) WL[BK + d] = t3 + cab[kC + d];
  {
    int h = d >> 4, o = d & 15, op = o >> 1;
    int q = (c & 1) * 2 + (op >> 2);
    ((unsigned short*)(WL + WKU))[h * 2048 + q * 512 + (c >> 1) * 8 + (op & 3) * 2 + (o & 1)] =
        f2h(wk * clg[c]);
  }

  // ---- V ----
  float wv = caw[(2 * kC + d) * kC + c];
  float t4 = redsum128(wv * clb[c], red2);
  if (c == 0) WL[BV + d] = t4 + cab[2 * kC + d];
  ((unsigned short*)(WL + WV2))[jstd] = f2h(wv * clg[c]);

  // ---- O (no fold, just pack) ----
  ((unsigned short*)(WL + WO2))[jstd] = f2h(cow[d * kC + c]);
}

// ---------------- kernel 3: bilinear warp + LN -> two f16 volumes + nearest mask --------
// One wave handles a BIN-PAIR (2 gathers) so it can emit both the scores volume
// (F2h [pix][bin][pair], coalesced 256B stores) and the bin-pair volume (F2hT
// [pix][bp][c], coalesced 512B stores). grid (1920, 32).
__global__ __launch_bounds__(256) void k_warp(const float* __restrict__ f2t,
                                              const float* __restrict__ coords,
                                              unsigned* __restrict__ F2h,
                                              unsigned* __restrict__ F2hT,
                                              float* __restrict__ maskout) {
  int wave = threadIdx.x >> 6, lane = threadIdx.x & 63;
  int pix = blockIdx.x * 4 + wave;
  int bpair = blockIdx.y;
  float ox[2], oy[2];
#pragma unroll
  for (int sub = 0; sub < 2; ++sub) {
    int b = 2 * bpair + sub;
    long long bp = (long long)b * kP + pix;
    float cx = coords[bp * 2], cy = coords[bp * 2 + 1];
    cx = (cx < -1.f) ? -2.f : cx;
    cx = (cx > 1.f) ? 2.f : cx;
    cy = (cy < -1.f) ? -2.f : cy;
    cy = (cy > 1.f) ? 2.f : cy;
    float gx = (cx + 1.f) * 0.5f * (float)(kW - 1);
    float gy = (cy + 1.f) * 0.5f * (float)(kH - 1);
    float x0f = floorf(gx), y0f = floorf(gy);
    float wx = gx - x0f, wy = gy - y0f;
    int x0 = (int)x0f, y0 = (int)y0f;
    int x1 = x0 + 1, y1 = y0 + 1;
    float vx0 = (x0 >= 0 && x0 < kW) ? 1.f : 0.f;
    float vx1 = (x1 >= 0 && x1 < kW) ? 1.f : 0.f;
    float vy0 = (y0 >= 0 && y0 < kH) ? 1.f : 0.f;
    float vy1 = (y1 >= 0 && y1 < kH) ? 1.f : 0.f;
    int x0c = min(max(x0, 0), kW - 1), x1c = min(max(x1, 0), kW - 1);
    int y0c = min(max(y0, 0), kH - 1), y1c = min(max(y1, 0), kH - 1);
    float w00 = (1.f - wy) * (1.f - wx) * vx0 * vy0;
    float w01 = (1.f - wy) * wx * vx1 * vy0;
    float w10 = wy * (1.f - wx) * vx0 * vy1;
    float w11 = wy * wx * vx1 * vy1;
    float2 g00 = ((const float2*)(f2t + (y0c * kW + x0c) * kC))[lane];
    float2 g01 = ((const float2*)(f2t + (y0c * kW + x1c) * kC))[lane];
    float2 g10 = ((const float2*)(f2t + (y1c * kW + x0c) * kC))[lane];
    float2 g11 = ((const float2*)(f2t + (y1c * kW + x1c) * kC))[lane];
    float v0 = w00 * g00.x + w01 * g01.x + w10 * g10.x + w11 * g11.x;
    float v1 = w00 * g00.y + w01 * g01.y + w10 * g10.y + w11 * g11.y;
    float s = v0 + v1, s2 = v0 * v0 + v1 * v1;
#pragma unroll
    for (int off = 32; off > 0; off >>= 1) {
      s += __shfl_xor(s, off);
      s2 += __shfl_xor(s2, off);
    }
    float m = s * (1.f / 128.f);
    float var = s2 * (1.f / 128.f) - m * m;
    float rs = rsqrtf(var + 1e-5f);
    ox[sub] = (v0 - m) * rs;
    oy[sub] = (v1 - m) * rs;
    // scores volume: [pix][bin][pair l] — coalesced 256 B per store
    F2h[(unsigned)pix * 4096u + (unsigned)b * 64u + lane] = pkrtz(ox[sub], oy[sub]);
    if (lane == 0) {
      int xi = (int)rintf(gx), yi = (int)rintf(gy);
      maskout[bp] = (xi >= 0 && xi < kW && yi >= 0 && yi < kH) ? 1.f : 0.f;
    }
  }
  // bin-pair volume: u32 [pix][bpair][c] = (f16 bin 2bp, f16 bin 2bp+1)
  uint2 st;
  st.x = pkrtz(ox[0], ox[1]);  // c = 2*lane
  st.y = pkrtz(oy[0], oy[1]);  // c = 2*lane+1
  *(uint2*)(F2hT + (unsigned)pix * 4096u + (unsigned)bpair * 128u + 2 * lane) = st;
}

// ---------------- kernel 4: fused warp+SSIM volume, rolling 3x3 column sums ----------------
__global__ __launch_bounds__(256) void k_ssim(const float* __restrict__ f1t,
                                              const float* __restrict__ f2t,
                                              const float* __restrict__ coords,
                                              float* __restrict__ ssimout) {
  const int lane = threadIdx.x & 63;
  const int y = blockIdx.x * 4 + (threadIdx.x >> 6);
  const int b = blockIdx.y;
  const int ym = (y == 0) ? 1 : y - 1;
  const int yp = (y == kH - 1) ? kH - 2 : y + 1;
  const long long bb = (long long)b * kP;
  const float* f1m = f1t + (ym * kW) * kC + 2 * lane;
  const float* f10 = f1t + (y * kW) * kC + 2 * lane;
  const float* f1p = f1t + (yp * kW) * kC + 2 * lane;
  float* outrow = ssimout + bb + y * kW;

  auto warp2 = [&](int yr, int x) -> f2v {
    long long bp = bb + yr * kW + x;
    float cx = coords[bp * 2], cy = coords[bp * 2 + 1];
    cx = (cx < -1.f) ? -2.f : cx;
    cx = (cx > 1.f) ? 2.f : cx;
    cy = (cy < -1.f) ? -2.f : cy;
    cy = (cy > 1.f) ? 2.f : cy;
    float gx = (cx + 1.f) * 0.5f * (float)(kW - 1);
    float gy = (cy + 1.f) * 0.5f * (float)(kH - 1);
    float x0f = floorf(gx), y0f = floorf(gy);
    float wx = gx - x0f, wy = gy - y0f;
    int x0 = (int)x0f, y0 = (int)y0f;
    int x1 = x0 + 1, y1 = y0 + 1;
    float vx0 = (x0 >= 0 && x0 < kW) ? 1.f : 0.f;
    float vx1 = (x1 >= 0 && x1 < kW) ? 1.f : 0.f;
    float vy0 = (y0 >= 0 && y0 < kH) ? 1.f : 0.f;
    float vy1 = (y1 >= 0 && y1 < kH) ? 1.f : 0.f;
    int x0c = min(max(x0, 0), kW - 1), x1c = min(max(x1, 0), kW - 1);
    int y0c = min(max(y0, 0), kH - 1), y1c = min(max(y1, 0), kH - 1);
    float w00 = (1.f - wy) * (1.f - wx) * vx0 * vy0;
    float w01 = (1.f - wy) * wx * vx1 * vy0;
    float w10 = wy * (1.f - wx) * vx0 * vy1;
    float w11 = wy * wx * vx1 * vy1;
    float2 g00 = ((const float2*)(f2t + (y0c * kW + x0c) * kC))[lane];
    float2 g01 = ((const float2*)(f2t + (y0c * kW + x1c) * kC))[lane];
    float2 g10 = ((const float2*)(f2t + (y1c * kW + x0c) * kC))[lane];
    float2 g11 = ((const float2*)(f2t + (y1c * kW + x1c) * kC))[lane];
    f2v r;
    r.x = w00 * g00.x + w01 * g01.x + w10 * g10.x + w11 * g11.x;
    r.y = w00 * g00.y + w01 * g01.y + w10 * g10.y + w11 * g11.y;
    return r;
  };

  f2v C[3][5];

  auto colsum = [&](int x, f2v* Cc) {
    f2v am = *(const f2v*)(f1m + (size_t)x * kC);
    f2v a0 = *(const f2v*)(f10 + (size_t)x * kC);
    f2v ap = *(const f2v*)(f1p + (size_t)x * kC);
    f2v wm = warp2(ym, x);
    f2v w0 = warp2(y, x);
    f2v wp = warp2(yp, x);
    Cc[0] = am + a0 + ap;
    Cc[1] = wm + w0 + wp;
    Cc[2] = am * am + a0 * a0 + ap * ap;
    Cc[3] = wm * wm + w0 * w0 + wp * wp;
    Cc[4] = am * wm + a0 * w0 + ap * wp;
  };

  auto emit = [&](int xo, f2v s0, f2v s1, f2v s2, f2v s3, f2v s4) {
    const float inv9 = 1.f / 9.f;
    f2v mx = s0 * inv9, my = s1 * inv9;
    f2v vx = s2 * inv9 - mx * mx;
    f2v vy = s3 * inv9 - my * my;
    f2v vxy = s4 * inv9 - mx * my;
    f2v num = (2.f * mx * my + 1e-4f) * (2.f * vxy + 9e-4f);
    f2v den = (mx * mx + my * my + 1e-4f) * (vx + vy + 9e-4f);
    f2v val = (1.f - num / den) * 0.5f;
    float t = fminf(fmaxf(val.x, 0.f), 1.f) + fminf(fmaxf(val.y, 0.f), 1.f);
#pragma unroll
    for (int o = 32; o > 0; o >>= 1) t += __shfl_xor(t, o);
    if (lane == 0) outrow[xo] = t * (1.f / 128.f);
  };

  colsum(0, C[0]);
  colsum(1, C[1]);
  emit(0, C[0][0] + 2.f * C[1][0], C[0][1] + 2.f * C[1][1], C[0][2] + 2.f * C[1][2],
       C[0][3] + 2.f * C[1][3], C[0][4] + 2.f * C[1][4]);
#pragma unroll 3
  for (int x = 2; x < kW; ++x) {
    colsum(x, C[x % 3]);
    emit(x - 1, C[0][0] + C[1][0] + C[2][0], C[0][1] + C[1][1] + C[2][1],
         C[0][2] + C[1][2] + C[2][2], C[0][3] + C[1][3] + C[2][3],
         C[0][4] + C[1][4] + C[2][4]);
  }
  emit(kW - 1, C[0][0] + 2.f * C[2][0], C[0][1] + 2.f * C[2][1], C[0][2] + 2.f * C[2][2],
       C[0][3] + 2.f * C[2][3], C[0][4] + 2.f * C[2][4]);
}

// ---------------- kernel 5: argmin over bins -> lowest_cost ----------------
__global__ __launch_bounds__(256) void k_argmin(const float* __restrict__ ssim,
                                                float* __restrict__ lc) {
  int pix = blockIdx.x * 256 + threadIdx.x;  // 7680 exact
  float best = ssim[pix];
  int bi = 0;
  for (int b = 1; b < kNB; b++) {
    float v = ssim[b * kP + pix];
    if (v < best) { best = v; bi = b; }
  }
  float depth = expf(-0.69314718f + (5.2983174f * (float)bi) / 63.0f);
  lc[pix] = 1.f / depth;
}

// ---------------- kernel 6: fused 6-layer transformer ----------------
// R5: 1 wave = 1 pixel = 1 block (64 thr), ZERO block barriers (R0 execution
// model + R4 math). F2 scores-layout in registers (sA, 64 VGPR); F2 wbar-layout
// in per-wave LDS (sBL 4 KB, staged once via global_load_lds). Weights streamed
// per-wave directly from L2 (no LDS staging -> no __syncthreads). Occupancy
// capped by regs (launch_bounds(64,3) -> <=170) at ~12 waves/CU, all independent.

__device__ __forceinline__ void ln_store(int l, f2v X, unsigned* xhq) {
  float s = X.x + X.y, s2 = X.x * X.x + X.y * X.y;
#pragma unroll
  for (int o = 32; o > 0; o >>= 1) { s += __shfl_xor(s, o); s2 += __shfl_xor(s2, o); }
  float m = s * 0.0078125f;
  float var = s2 * 0.0078125f - m * m;
  float rs = rsqrtf(var + 1e-5f);
  xhq[l] = pkrtz((X.x - m) * rs, (X.y - m) * rs);
}

__device__ __forceinline__ void dot16(uint4 inA, uint4 inB, uint4 wa, uint4 wc,
                                      uint4 wa2, uint4 wc2,
                                      float& a0, float& a1, float& c0, float& c1) {
  a0 = fdot2(inA.x, wa.x, a0);  a0 = fdot2(inA.y, wa.y, a0);
  a0 = fdot2(inA.z, wa.z, a0);  a0 = fdot2(inA.w, wa.w, a0);
  a1 = fdot2(inA.x, wc.x, a1);  a1 = fdot2(inA.y, wc.y, a1);
  a1 = fdot2(inA.z, wc.z, a1);  a1 = fdot2(inA.w, wc.w, a1);
  c0 = fdot2(inB.x, wa2.x, c0); c0 = fdot2(inB.y, wa2.y, c0);
  c0 = fdot2(inB.z, wa2.z, c0); c0 = fdot2(inB.w, wa2.w, c0);
  c1 = fdot2(inB.x, wc2.x, c1); c1 = fdot2(inB.y, wc2.y, c1);
  c1 = fdot2(inB.z, wc2.z, c1); c1 = fdot2(inB.w, wc2.w, c1);
}

// full 128x128 std gemm, weights streamed from global (layout per k_fold)
__device__ __forceinline__ f2v gemmW_g(const unsigned* __restrict__ inb,
                                       const unsigned* __restrict__ Wg, int l,
                                       float b0, float b1) {
  float a0 = b0, a1 = b1, c0 = 0.f, c1 = 0.f;
  const unsigned* wp = Wg + l * 4;
#pragma unroll
  for (int j = 0; j < 16; j += 2) {
    uint4 inA = *(const uint4*)(inb + 4 * j);
    uint4 inB = *(const uint4*)(inb + 4 * j + 4);
    const unsigned* w0 = wp + j * 512;
    uint4 wa = *(const uint4*)(w0);
    uint4 wc = *(const uint4*)(w0 + 256);
    uint4 wa2 = *(const uint4*)(w0 + 512);
    uint4 wc2 = *(const uint4*)(w0 + 768);
    dot16(inA, inB, wa, wc, wa2, wc2, a0, a1, c0, c1);
  }
  f2v r; r.x = a0 + c0; r.y = a1 + c1; return r;
}

__global__ __launch_bounds__(64, 3) void k_attn(const unsigned* __restrict__ F2h,
                                                const unsigned* __restrict__ F2hT,
                                                const float* __restrict__ f1t,
                                                const float* __restrict__ wts,
                                                const float* __restrict__ cab_out,
                                                float* __restrict__ attn_out) {
  // per-wave LDS: upb (u / p_hi+p_lo / wbar / rawh, 512 u32) + xhq (64 u32)
  __shared__ __align__(16) unsigned upb[576];
  // per-wave F2 transpose copy [bp 0..31][c 0..127] u32 (bin-pairs per channel)
  __shared__ __align__(16) unsigned sBL[1024];

  const int l = threadIdx.x;
  const int pix = blockIdx.x;
  unsigned* xhq = upb + 512;
  float* pf = (float*)upb;

  const int mrow = l & 31;   // bin row within tile (also MFMA C col = head for n<8)
  const int kg = l >> 5;     // MFMA k-group
  const int rbase = 4 * kg;  // MFMA C row base

  f2v X;
  { float2 xv = ((const float2*)(f1t + (long long)pix * kC))[l]; X.x = xv.x; X.y = xv.y; }

  // ---- prologue: F2 scores-layout -> registers; F2 wbar-layout -> LDS ----
  h8 sA0[8], sA1[8];
  {
    const unsigned* F2a = F2h + (unsigned)pix * 4096u + mrow * 64 + kg * 4;
#pragma unroll
    for (int kc = 0; kc < 8; ++kc) {
      sA0[kc] = *(const h8*)(F2a + kc * 8);
      sA1[kc] = *(const h8*)(F2a + 32 * 64 + kc * 8);
    }
  }
  {
    const unsigned* Ts = F2hT + (unsigned)pix * 4096u + l * 4;
#pragma unroll
    for (int i = 0; i < 16; ++i) gl_lds16(Ts + i * 256, sBL + i * 256);
    __asm__ __volatile__("s_waitcnt vmcnt(0)" ::: "memory");
    __builtin_amdgcn_sched_barrier(0);
  }

  float chsum = 0.f;
  for (int ly = 0; ly < kNL; ++ly) {
    const float* WL = wts + (long long)ly * WTS_STRIDE;
    const bool last = (ly == kNL - 1);

    // ---- LN(SA) -> xhq ; SA gemm ; residual ----
    ln_store(l, X, xhq);
    wb();
    {
      float2 bv = ((const float2*)(WL + BSA))[l];
      f2v o = gemmW_g(xhq, (const unsigned*)(WL + WSA2), l, bv.x, bv.y);
      X += o;
    }
    wb();
    // ---- LN(CA) -> xhq ; Q gemm ----
    ln_store(l, X, xhq);
    wb();
    f2v q;
    {
      float2 bv = ((const float2*)(WL + BQ))[l];
      q = gemmW_g(xhq, (const unsigned*)(WL + WQ2), l, bv.x, bv.y);
    }
    if (last) {  // k-bias contribution to raw: full dot q.bk
      float2 bk = ((const float2*)(WL + BK))[l];
      float cp = q.x * bk.x + q.y * bk.y;
#pragma unroll
      for (int o = 32; o > 0; o >>= 1) cp += __shfl_xor(cp, o);
      chsum = cp;
    }
    xhq[l] = pkrtz(q.x, q.y);  // qpk (d-pairs == o-pairs)
    wb();

    // ---- U: u[h][c-pair l] = sum_o q[h*16+o] * Wk'[h*16+o][c]; store col ^ 4h ----
    {
      const unsigned* KU = (const unsigned*)(WL + WKU);
#pragma unroll
      for (int h = 0; h < kNH; ++h) {
        uint4 q0 = *(const uint4*)(xhq + h * 8);      // o-pairs 0..3 (broadcast)
        uint4 q1 = *(const uint4*)(xhq + h * 8 + 4);  // o-pairs 4..7
        const unsigned* w0 = KU + h * 1024 + l * 4;
        uint4 av0 = *(const uint4*)(w0);
        uint4 av1 = *(const uint4*)(w0 + 256);
        uint4 bv0 = *(const uint4*)(w0 + 512);
        uint4 bv1 = *(const uint4*)(w0 + 768);
        float u0 = 0.f, u1 = 0.f, u2 = 0.f, u3 = 0.f;
        u0 = fdot2(q0.x, av0.x, u0); u0 = fdot2(q0.y, av0.y, u0);
        u0 = fdot2(q0.z, av0.z, u0); u0 = fdot2(q0.w, av0.w, u0);
        u2 = fdot2(q1.x, av1.x, u2); u2 = fdot2(q1.y, av1.y, u2);
        u2 = fdot2(q1.z, av1.z, u2); u2 = fdot2(q1.w, av1.w, u2);
        u1 = fdot2(q0.x, bv0.x, u1); u1 = fdot2(q0.y, bv0.y, u1);
        u1 = fdot2(q0.z, bv0.z, u1); u1 = fdot2(q0.w, bv0.w, u1);
        u3 = fdot2(q1.x, bv1.x, u3); u3 = fdot2(q1.y, bv1.y, u3);
        u3 = fdot2(q1.z, bv1.z, u3); u3 = fdot2(q1.w, bv1.w, u3);
        upb[h * 64 + (l ^ (4 * h))] = pkrtz(u0 + u2, u1 + u3);
      }
    }
    wb();

    // ---- scores via MFMA: C[bin][head] = F2 @ u; A from registers ----
    fx16 acc0 = (fx16)0.f, acc1 = (fx16)0.f;
    {
      const int hn = mrow & 7;          // clamp head for n>=8 lanes (dup cols, ignored)
      const int usw = 4 * hn;           // u row swizzle
#pragma unroll
      for (int kc = 0; kc < 8; ++kc) {
        const int cp = kc * 8 + kg * 4;  // u32 column of channel k0 = kc*16+kg*8
        h8 Bv = *(const h8*)(upb + hn * 64 + (cp ^ usw));
        acc0 = __builtin_amdgcn_mfma_f32_32x32x16_f16(sA0[kc], Bv, acc0, 0, 0, 0);
        acc1 = __builtin_amdgcn_mfma_f32_32x32x16_f16(sA1[kc], Bv, acc1, 0, 0, 0);
      }
    }
    if (last) {
      // raw[bin] = sum_h sc[bin][h] + chsum; redistribute via pf as rawh[8][64]
      wb();
      if (mrow < 8) {
#pragma unroll
        for (int r = 0; r < 16; ++r) {
          int row = (r & 3) + 8 * (r >> 2) + rbase;
          pf[mrow * 64 + row] = acc0[r];
          pf[mrow * 64 + 32 + row] = acc1[r];
        }
      }
      wb();
      float rsum = chsum;
#pragma unroll
      for (int h = 0; h < kNH; ++h) rsum += pf[h * 64 + l];
      attn_out[(long long)pix * 64 + l] = rsum;
      return;
    }
    // ---- softmax over bins: head h lives in lanes {h, h+32} (16+16 rows each) ----
    // p stored to LDS as hi/lo f16 bin-pairs: p_hi [8h][36-padded bpair] at upb+0,
    // p_lo at upb+288 (spills into xhq region — q already consumed).
    {
      float mx = acc0[0];
#pragma unroll
      for (int r = 0; r < 16; ++r) { mx = fmaxf(mx, acc0[r]); mx = fmaxf(mx, acc1[r]); }
      mx = fmaxf(mx, __shfl_xor(mx, 32));
      float pv0[16], pv1[16];
      float sm = 0.f;
#pragma unroll
      for (int r = 0; r < 16; ++r) {
        pv0[r] = __expf(acc0[r] - mx); sm += pv0[r];
        pv1[r] = __expf(acc1[r] - mx); sm += pv1[r];
      }
      sm += __shfl_xor(sm, 32);
      float inv = 1.f / sm;
      wb();  // all u (B-frag) reads complete before p overwrites upb
      if (mrow < 8) {
#pragma unroll
        for (int r = 0; r < 16; r += 2) {
          int row = (r & 3) + 8 * (r >> 2) + rbase;  // bins row, row+1 (row even)
          int bp = row >> 1;
          float x0 = pv0[r] * inv, x1 = pv0[r + 1] * inv;
          unsigned uh = pkrtz(x0, x1); f2v bk = h2f(uh);
          unsigned ul = pkrtz(x0 - bk.x, x1 - bk.y);
          upb[mrow * 36 + bp] = uh;
          upb[288 + mrow * 36 + bp] = ul;
          float y0 = pv1[r] * inv, y1 = pv1[r + 1] * inv;  // bins +32
          unsigned vh = pkrtz(y0, y1); f2v bk2 = h2f(vh);
          unsigned vl = pkrtz(y0 - bk2.x, y1 - bk2.y);
          upb[mrow * 36 + 16 + bp] = vh;
          upb[288 + mrow * 36 + 16 + bp] = vl;
        }
      }
    }
    wb();
    // ---- wbar via MFMA: D[c][h] = sum_b F2[b][c] p[b][h]; A-frags from sBL ----
    {
      const int hb = mrow & 7;
      h8 ph[4], pl[4];
#pragma unroll
      for (int ks = 0; ks < 4; ++ks) {
        ph[ks] = *(const h8*)(upb + hb * 36 + ks * 8 + kg * 4);
        pl[ks] = *(const h8*)(upb + 288 + hb * 36 + ks * 8 + kg * 4);
      }
      wb();
      const bool wval = mrow < 8;
#pragma unroll
      for (int ct = 0; ct < 4; ++ct) {
        fx16 a = (fx16)0.f;
#pragma unroll
        for (int ks = 0; ks < 4; ++ks) {
          union { unsigned u[4]; h8 h; } t;
#pragma unroll
          for (int j = 0; j < 4; ++j)
            t.u[j] = sBL[(ks * 8 + kg * 4 + j) * 128 + ct * 32 + (l & 31)];
          a = __builtin_amdgcn_mfma_f32_32x32x16_f16(t.h, ph[ks], a, 0, 0, 0);
          a = __builtin_amdgcn_mfma_f32_32x32x16_f16(t.h, pl[ks], a, 0, 0, 0);
        }
        if (wval) {
#pragma unroll
          for (int r = 0; r < 16; r += 2) {
            int m = (r & 3) + 8 * (r >> 2) + rbase;  // channel-in-tile (even)
            int cpair = ct * 16 + (m >> 1);
            upb[mrow * 64 + (cpair ^ (4 * mrow))] = pkrtz(a[r], a[r + 1]);
          }
        }
      }
    }
    wb();
    // ---- AO: ao[d] = wbar[h(d)] . Wv'[:,d] + bv (weights streamed) ----
    {
      const int h = l >> 3, sw = 4 * h;  // d=2l -> head
      const unsigned* wrow = upb + h * 64;
      const unsigned* WV = (const unsigned*)(WL + WV2) + l * 4;
      float2 bv = ((const float2*)(WL + BV))[l];
      float a0 = bv.x, a1 = bv.y, c0 = 0.f, c1 = 0.f;
#pragma unroll
      for (int j = 0; j < 16; j += 2) {
        uint4 inA = *(const uint4*)(wrow + ((4 * j) ^ sw));
        uint4 inB = *(const uint4*)(wrow + ((4 * j + 4) ^ sw));
        const unsigned* w0 = WV + j * 512;
        uint4 wa = *(const uint4*)(w0);
        uint4 wc = *(const uint4*)(w0 + 256);
        uint4 wa2 = *(const uint4*)(w0 + 512);
        uint4 wc2 = *(const uint4*)(w0 + 768);
        dot16(inA, inB, wa, wc, wa2, wc2, a0, a1, c0, c1);
      }
      xhq[l] = pkrtz(a0 + c0, a1 + c1);
    }
    wb();
    // ---- O: X += ao @ Wo^T + bo ----
    {
      float2 bv = ((const float2*)(cab_out + ly * kC))[l];
      f2v o = gemmW_g(xhq, (const unsigned*)(WL + WO2), l, bv.x, bv.y);
      X += o;
    }
    wb();
  }
}

// ---------------- launch ----------------
extern "C" void kernel_launch(void* const* d_in, const int* in_sizes, int n_in, void* d_out,
                              int out_size, void* d_ws, size_t ws_size, hipStream_t stream) {
  (void)in_sizes; (void)n_in; (void)out_size; (void)ws_size;
  const float* feat1 = (const float*)d_in[0];
  const float* feat2 = (const float*)d_in[1];
  const float* coords = (const float*)d_in[2];
  const float* sa_in_w = (const float*)d_in[3];
  const float* sa_in_b = (const float*)d_in[4];
  const float* sa_out_w = (const float*)d_in[5];
  const float* sa_out_b = (const float*)d_in[6];
  const float* sa_ln_g = (const float*)d_in[7];
  const float* sa_ln_b = (const float*)d_in[8];
  const float* ca_in_w = (const float*)d_in[9];
  const float* ca_in_b = (const float*)d_in[10];
  const float* ca_out_w = (const float*)d_in[11];
  const float* ca_out_b = (const float*)d_in[12];
  const float* ca_ln_g = (const float*)d_in[13];
  const float* ca_ln_b = (const float*)d_in[14];

  float* out = (float*)d_out;
  float* ws = (float*)d_ws;
  float* f1t = ws + OFF_F1T;
  float* f2t = ws + OFF_F2T;
  float* wts = ws + OFF_WTS;
  unsigned* F2h = (unsigned*)(ws + OFF_F2H);
  unsigned* F2hT = (unsigned*)(ws + OFF_F2HT);

  float* att = out + OUT_ATT;
  float* mask = out + OUT_MASK;
  float* lc = out + OUT_LC;
  float* ssim = out + OUT_SSIM;

  dim3 gt(240, 4);
  k_transpose<<<gt, 256, 0, stream>>>(feat1, feat2, f1t, f2t);
  k_fold<<<kNL * 128, 128, 0, stream>>>(sa_in_w, sa_in_b, sa_out_w, sa_out_b, sa_ln_g, sa_ln_b,
                                        ca_in_w, ca_in_b, ca_ln_g, ca_ln_b, ca_out_w, wts);
  dim3 g1(1920, 32);
  k_warp<<<g1, 256, 0, stream>>>(f2t, coords, F2h, F2hT, mask);
  dim3 g2(12, 64);
  k_ssim<<<g2, 256, 0, stream>>>(f1t, f2t, coords, ssim);
  k_argmin<<<30, 256, 0, stream>>>(ssim, lc);
  k_attn<<<kP, 64, 0, stream>>>(F2h, F2hT, f1t, wts, ca_out_b, att);
}

// Round 6
// 921.986 us; speedup vs baseline: 1.1717x; 1.1717x over previous
//
#include <hip/hip_runtime.h>

// ---------------- problem constants (fixed by setup_inputs) ----------------
constexpr int kH  = 48;
constexpr int kW  = 160;
constexpr int kP  = 7680;   // kH*kW
constexpr int kC  = 128;
constexpr int kNB = 64;
constexpr int kNH = 8;
constexpr int kNL = 6;

// workspace layout (in floats) — total ~260 MB (R4-proven extent)
constexpr long long OFF_F1T = 0;
constexpr long long OFF_F2T = 983040;
constexpr long long OFF_WTS = 1966080;
// per-layer folded weight block (element offsets, elements are 4 B).
// std matrices (SA/Q/V/O): u16 idx = (c>>3)*1024 + (d&1)*512 + (d>>1)*8 + (c&7)
//   -> per j-chunk: [2 d-parity][64 lane][4 u32], lane stride 16 B
// WKU: u16 idx = h*2048 + q*512 + (c>>1)*8 + (op&3)*2 + (o&1), q=(c&1)*2+(op>>2)
// Chunk view: weights = 20 chunks x 2048 u32 (SA 0-3, Q 4-7, KU 8-11, V 12-15, O 16-19)
constexpr int WSA2 = 0;
constexpr int WQ2  = 8192;
constexpr int WKU  = 16384;
constexpr int WV2  = 24576;
constexpr int WO2  = 32768;
constexpr int BSA  = 40960;    // f32 [128]
constexpr int BQ   = 41088;
constexpr int BK   = 41216;
constexpr int BV   = 41344;
constexpr int WTS_STRIDE = 41472;
// f16x2 scores volume: u32 idx = pix*4096 + bin*64 + pair   (126 MB, coalesced)
constexpr long long OFF_F2H  = OFF_WTS + 6LL * WTS_STRIDE;          // 2214912
// f16x2 bin-pair volume: u32 idx = pix*4096 + bp*128 + c    (126 MB)
constexpr long long OFF_F2HT = OFF_F2H + 31457280LL;

// d_out regions (floats)
constexpr long long OUT_ATT  = 0;         // (1,48,160,64)
constexpr long long OUT_MASK = 491520;    // (64,1,48,160)
constexpr long long OUT_LC   = 983040;    // (1,48,160)
constexpr long long OUT_SSIM = 990720;    // (1,64,48,160)

// ---------------- helpers ----------------
typedef _Float16 h2v __attribute__((ext_vector_type(2)));
typedef __fp16 p2v __attribute__((ext_vector_type(2)));
typedef float f2v __attribute__((ext_vector_type(2)));
typedef __fp16 h8 __attribute__((ext_vector_type(8)));
typedef float fx16 __attribute__((ext_vector_type(16)));
union U32H2 { unsigned u; h2v h; };
union U32P2 { unsigned u; p2v h; };

__device__ __forceinline__ float fdot2(unsigned a, unsigned b, float c) {
  U32H2 ua; ua.u = a; U32H2 ub; ub.u = b;
  return __builtin_amdgcn_fdot2(ua.h, ub.h, c, false);
}
__device__ __forceinline__ unsigned pkrtz(float a, float b) {
  U32P2 t; t.h = __builtin_amdgcn_cvt_pkrtz(a, b); return t.u;
}
__device__ __forceinline__ f2v h2f(unsigned u) {
  U32P2 t; t.u = u; f2v r; r.x = (float)t.h.x; r.y = (float)t.h.y; return r;
}
__device__ __forceinline__ unsigned short f2h(float x) {
  U32P2 t; t.h = __builtin_amdgcn_cvt_pkrtz(x, 0.f); return (unsigned short)(t.u & 0xffffu);
}
// compiler-order pin for wave-internal LDS producer->consumer (HW LDS is in-order per wave)
__device__ __forceinline__ void wb() {
  __asm__ __volatile__("" ::: "memory");
  __builtin_amdgcn_wave_barrier();
  __asm__ __volatile__("" ::: "memory");
}

// async global->LDS: 16 B per lane; LDS dest = uniform base + lane*16
typedef __attribute__((address_space(1))) const void gvoid_t;
typedef __attribute__((address_space(3))) void svoid_t;
__device__ __forceinline__ void gl_lds16(const unsigned* g, unsigned* s) {
  __builtin_amdgcn_global_load_lds((gvoid_t*)g, (svoid_t*)s, 16, 0, 0);
}

// stage global chunk id g (layer g/20, chunk g%20) into ring slot g&7; wave w stages 2 KB
__device__ __forceinline__ void stage_g(const unsigned* wts32, int g, unsigned* wball,
                                        int w, int l) {
  int ly = g / 20, ck = g - ly * 20;
  const unsigned* s = wts32 + ly * WTS_STRIDE + ck * 2048 + w * 512 + l * 4;
  unsigned* d = wball + (g & 7) * 2048 + w * 512;
  gl_lds16(s, d);
  gl_lds16(s + 256, d + 256);
}

// counted-vmcnt barrier: chunk c ready once <=12 newer loads (chunks c+1..c+6) remain.
// vmcnt is in-order per wave; "memory" clobber + sched_barrier stop hoisting across it.
__device__ __forceinline__ void chunk_wait() {
  __builtin_amdgcn_sched_barrier(0);
  __asm__ __volatile__("s_waitcnt vmcnt(12)" ::: "memory");
  __builtin_amdgcn_sched_barrier(0);
  __builtin_amdgcn_s_barrier();
  __builtin_amdgcn_sched_barrier(0);
  __asm__ __volatile__("" ::: "memory");
}

// ---------------- kernel 1: NCHW -> [pix][c] transpose, LDS-tiled ----------------
__global__ __launch_bounds__(256) void k_transpose(const float* __restrict__ feat1,
                                                   const float* __restrict__ feat2,
                                                   float* __restrict__ f1t,
                                                   float* __restrict__ f2t) {
  __shared__ float t1[32][33], t2[32][33];
  const int p0 = blockIdx.x * 32, c0 = blockIdx.y * 32;
  const int r = threadIdx.x >> 5, col = threadIdx.x & 31;
#pragma unroll
  for (int rr = r; rr < 32; rr += 8) {
    t1[rr][col] = feat1[(c0 + rr) * kP + p0 + col];
    t2[rr][col] = feat2[(c0 + rr) * kP + p0 + col];
  }
  __syncthreads();
#pragma unroll
  for (int rr = r; rr < 32; rr += 8) {
    f1t[(p0 + rr) * kC + c0 + col] = t1[col][rr];
    f2t[(p0 + rr) * kC + c0 + col] = t2[col][rr];
  }
}

// ---------------- kernel 2: fold LN gamma/beta + combine SA Wo@Wv, pack f16 ----------------
__device__ __forceinline__ float redsum128(float v, float* red2) {
#pragma unroll
  for (int off = 32; off > 0; off >>= 1) v += __shfl_xor(v, off);
  int t = threadIdx.x;
  if ((t & 63) == 0) red2[t >> 6] = v;
  __syncthreads();
  float r = red2[0] + red2[1];
  __syncthreads();
  return r;
}

__global__ __launch_bounds__(128) void k_fold(
    const float* __restrict__ saw_, const float* __restrict__ sab_,
    const float* __restrict__ sow_, const float* __restrict__ sob_,
    const float* __restrict__ slg_, const float* __restrict__ slb_,
    const float* __restrict__ caw_, const float* __restrict__ cab_,
    const float* __restrict__ clg_, const float* __restrict__ clb_,
    const float* __restrict__ cow_, float* __restrict__ wts) {
  int i = blockIdx.x >> 7, d = blockIdx.x & 127, c = threadIdx.x;
  const float* saw = saw_ + (long long)i * 384 * kC;
  const float* sab = sab_ + i * 384;
  const float* sow = sow_ + i * kC * kC;
  const float* sob = sob_ + i * kC;
  const float* slg = slg_ + i * kC;
  const float* slb = slb_ + i * kC;
  const float* caw = caw_ + (long long)i * 384 * kC;
  const float* cab = cab_ + i * 384;
  const float* clg = clg_ + i * kC;
  const float* clb = clb_ + i * kC;
  const float* cow = cow_ + i * kC * kC;
  float* WL = wts + (long long)i * WTS_STRIDE;
  __shared__ float red2[2];

  // std matrix u16 index for (c,d): per-j [2 parity][64 lane][8 u16]
  int jstd = (c >> 3) * 1024 + (d & 1) * 512 + (d >> 1) * 8 + (c & 7);

  // ---- SA: Wsa_pre = Wo_sa @ Wv_sa, fold ln gamma/beta ----
  float acc = 0.f;
  for (int m = 0; m < kC; m++) acc += sow[d * kC + m] * saw[(256 + m) * kC + c];
  float t1 = redsum128(acc * slb[c] + sow[d * kC + c] * sab[256 + c], red2);
  if (c == 0) WL[BSA + d] = t1 + sob[d];
  ((unsigned short*)(WL + WSA2))[jstd] = f2h(acc * slg[c]);

  // ---- Q (x0.25 fold) ----
  float wq = caw[d * kC + c];
  float t2 = redsum128(wq * clb[c], red2);
  if (c == 0) WL[BQ + d] = 0.25f * (t2 + cab[d]);
  ((unsigned short*)(WL + WQ2))[jstd] = f2h(0.25f * wq * clg[c]);

  // ---- K -> WKU [h][4 q][64 lane][4 u32] ----
  float wk = caw[(kC + d) * kC + c];
  float t3 = redsum128(wk * clb[c], red2);
  if (c == 0) WL[BK + d] = t3 + cab[kC + d];
  {
    int h = d >> 4, o = d & 15, op = o >> 1;
    int q = (c & 1) * 2 + (op >> 2);
    ((unsigned short*)(WL + WKU))[h * 2048 + q * 512 + (c >> 1) * 8 + (op & 3) * 2 + (o & 1)] =
        f2h(wk * clg[c]);
  }

  // ---- V ----
  float wv = caw[(2 * kC + d) * kC + c];
  float t4 = redsum128(wv * clb[c], red2);
  if (c == 0) WL[BV + d] = t4 + cab[2 * kC + d];
  ((unsigned short*)(WL + WV2))[jstd] = f2h(wv * clg[c]);

  // ---- O (no fold, just pack) ----
  ((unsigned short*)(WL + WO2))[jstd] = f2h(cow[d * kC + c]);
}

// ---------------- kernel 3: bilinear warp + LN -> two f16 volumes + nearest mask --------
// One wave handles a BIN-PAIR (2 gathers) so it can emit both the scores volume
// (F2h [pix][bin][pair], coalesced 256B stores) and the bin-pair volume (F2hT
// [pix][bp][c], coalesced 512B stores). grid (1920, 32).
__global__ __launch_bounds__(256) void k_warp(const float* __restrict__ f2t,
                                              const float* __restrict__ coords,
                                              unsigned* __restrict__ F2h,
                                              unsigned* __restrict__ F2hT,
                                              float* __restrict__ maskout) {
  int wave = threadIdx.x >> 6, lane = threadIdx.x & 63;
  int pix = blockIdx.x * 4 + wave;
  int bpair = blockIdx.y;
  float ox[2], oy[2];
#pragma unroll
  for (int sub = 0; sub < 2; ++sub) {
    int b = 2 * bpair + sub;
    long long bp = (long long)b * kP + pix;
    float cx = coords[bp * 2], cy = coords[bp * 2 + 1];
    cx = (cx < -1.f) ? -2.f : cx;
    cx = (cx > 1.f) ? 2.f : cx;
    cy = (cy < -1.f) ? -2.f : cy;
    cy = (cy > 1.f) ? 2.f : cy;
    float gx = (cx + 1.f) * 0.5f * (float)(kW - 1);
    float gy = (cy + 1.f) * 0.5f * (float)(kH - 1);
    float x0f = floorf(gx), y0f = floorf(gy);
    float wx = gx - x0f, wy = gy - y0f;
    int x0 = (int)x0f, y0 = (int)y0f;
    int x1 = x0 + 1, y1 = y0 + 1;
    float vx0 = (x0 >= 0 && x0 < kW) ? 1.f : 0.f;
    float vx1 = (x1 >= 0 && x1 < kW) ? 1.f : 0.f;
    float vy0 = (y0 >= 0 && y0 < kH) ? 1.f : 0.f;
    float vy1 = (y1 >= 0 && y1 < kH) ? 1.f : 0.f;
    int x0c = min(max(x0, 0), kW - 1), x1c = min(max(x1, 0), kW - 1);
    int y0c = min(max(y0, 0), kH - 1), y1c = min(max(y1, 0), kH - 1);
    float w00 = (1.f - wy) * (1.f - wx) * vx0 * vy0;
    float w01 = (1.f - wy) * wx * vx1 * vy0;
    float w10 = wy * (1.f - wx) * vx0 * vy1;
    float w11 = wy * wx * vx1 * vy1;
    float2 g00 = ((const float2*)(f2t + (y0c * kW + x0c) * kC))[lane];
    float2 g01 = ((const float2*)(f2t + (y0c * kW + x1c) * kC))[lane];
    float2 g10 = ((const float2*)(f2t + (y1c * kW + x0c) * kC))[lane];
    float2 g11 = ((const float2*)(f2t + (y1c * kW + x1c) * kC))[lane];
    float v0 = w00 * g00.x + w01 * g01.x + w10 * g10.x + w11 * g11.x;
    float v1 = w00 * g00.y + w01 * g01.y + w10 * g10.y + w11 * g11.y;
    float s = v0 + v1, s2 = v0 * v0 + v1 * v1;
#pragma unroll
    for (int off = 32; off > 0; off >>= 1) {
      s += __shfl_xor(s, off);
      s2 += __shfl_xor(s2, off);
    }
    float m = s * (1.f / 128.f);
    float var = s2 * (1.f / 128.f) - m * m;
    float rs = rsqrtf(var + 1e-5f);
    ox[sub] = (v0 - m) * rs;
    oy[sub] = (v1 - m) * rs;
    // scores volume: [pix][bin][pair l] — coalesced 256 B per store
    F2h[(unsigned)pix * 4096u + (unsigned)b * 64u + lane] = pkrtz(ox[sub], oy[sub]);
    if (lane == 0) {
      int xi = (int)rintf(gx), yi = (int)rintf(gy);
      maskout[bp] = (xi >= 0 && xi < kW && yi >= 0 && yi < kH) ? 1.f : 0.f;
    }
  }
  // bin-pair volume: u32 [pix][bpair][c] = (f16 bin 2bp, f16 bin 2bp+1)
  uint2 st;
  st.x = pkrtz(ox[0], ox[1]);  // c = 2*lane
  st.y = pkrtz(oy[0], oy[1]);  // c = 2*lane+1
  *(uint2*)(F2hT + (unsigned)pix * 4096u + (unsigned)bpair * 128u + 2 * lane) = st;
}

// ---------------- kernel 4: fused warp+SSIM volume, rolling 3x3 column sums ----------------
__global__ __launch_bounds__(256) void k_ssim(const float* __restrict__ f1t,
                                              const float* __restrict__ f2t,
                                              const float* __restrict__ coords,
                                              float* __restrict__ ssimout) {
  const int lane = threadIdx.x & 63;
  const int y = blockIdx.x * 4 + (threadIdx.x >> 6);
  const int b = blockIdx.y;
  const int ym = (y == 0) ? 1 : y - 1;
  const int yp = (y == kH - 1) ? kH - 2 : y + 1;
  const long long bb = (long long)b * kP;
  const float* f1m = f1t + (ym * kW) * kC + 2 * lane;
  const float* f10 = f1t + (y * kW) * kC + 2 * lane;
  const float* f1p = f1t + (yp * kW) * kC + 2 * lane;
  float* outrow = ssimout + bb + y * kW;

  auto warp2 = [&](int yr, int x) -> f2v {
    long long bp = bb + yr * kW + x;
    float cx = coords[bp * 2], cy = coords[bp * 2 + 1];
    cx = (cx < -1.f) ? -2.f : cx;
    cx = (cx > 1.f) ? 2.f : cx;
    cy = (cy < -1.f) ? -2.f : cy;
    cy = (cy > 1.f) ? 2.f : cy;
    float gx = (cx + 1.f) * 0.5f * (float)(kW - 1);
    float gy = (cy + 1.f) * 0.5f * (float)(kH - 1);
    float x0f = floorf(gx), y0f = floorf(gy);
    float wx = gx - x0f, wy = gy - y0f;
    int x0 = (int)x0f, y0 = (int)y0f;
    int x1 = x0 + 1, y1 = y0 + 1;
    float vx0 = (x0 >= 0 && x0 < kW) ? 1.f : 0.f;
    float vx1 = (x1 >= 0 && x1 < kW) ? 1.f : 0.f;
    float vy0 = (y0 >= 0 && y0 < kH) ? 1.f : 0.f;
    float vy1 = (y1 >= 0 && y1 < kH) ? 1.f : 0.f;
    int x0c = min(max(x0, 0), kW - 1), x1c = min(max(x1, 0), kW - 1);
    int y0c = min(max(y0, 0), kH - 1), y1c = min(max(y1, 0), kH - 1);
    float w00 = (1.f - wy) * (1.f - wx) * vx0 * vy0;
    float w01 = (1.f - wy) * wx * vx1 * vy0;
    float w10 = wy * (1.f - wx) * vx0 * vy1;
    float w11 = wy * wx * vx1 * vy1;
    float2 g00 = ((const float2*)(f2t + (y0c * kW + x0c) * kC))[lane];
    float2 g01 = ((const float2*)(f2t + (y0c * kW + x1c) * kC))[lane];
    float2 g10 = ((const float2*)(f2t + (y1c * kW + x0c) * kC))[lane];
    float2 g11 = ((const float2*)(f2t + (y1c * kW + x1c) * kC))[lane];
    f2v r;
    r.x = w00 * g00.x + w01 * g01.x + w10 * g10.x + w11 * g11.x;
    r.y = w00 * g00.y + w01 * g01.y + w10 * g10.y + w11 * g11.y;
    return r;
  };

  f2v C[3][5];

  auto colsum = [&](int x, f2v* Cc) {
    f2v am = *(const f2v*)(f1m + (size_t)x * kC);
    f2v a0 = *(const f2v*)(f10 + (size_t)x * kC);
    f2v ap = *(const f2v*)(f1p + (size_t)x * kC);
    f2v wm = warp2(ym, x);
    f2v w0 = warp2(y, x);
    f2v wp = warp2(yp, x);
    Cc[0] = am + a0 + ap;
    Cc[1] = wm + w0 + wp;
    Cc[2] = am * am + a0 * a0 + ap * ap;
    Cc[3] = wm * wm + w0 * w0 + wp * wp;
    Cc[4] = am * wm + a0 * w0 + ap * wp;
  };

  auto emit = [&](int xo, f2v s0, f2v s1, f2v s2, f2v s3, f2v s4) {
    const float inv9 = 1.f / 9.f;
    f2v mx = s0 * inv9, my = s1 * inv9;
    f2v vx = s2 * inv9 - mx * mx;
    f2v vy = s3 * inv9 - my * my;
    f2v vxy = s4 * inv9 - mx * my;
    f2v num = (2.f * mx * my + 1e-4f) * (2.f * vxy + 9e-4f);
    f2v den = (mx * mx + my * my + 1e-4f) * (vx + vy + 9e-4f);
    f2v val = (1.f - num / den) * 0.5f;
    float t = fminf(fmaxf(val.x, 0.f), 1.f) + fminf(fmaxf(val.y, 0.f), 1.f);
#pragma unroll
    for (int o = 32; o > 0; o >>= 1) t += __shfl_xor(t, o);
    if (lane == 0) outrow[xo] = t * (1.f / 128.f);
  };

  colsum(0, C[0]);
  colsum(1, C[1]);
  emit(0, C[0][0] + 2.f * C[1][0], C[0][1] + 2.f * C[1][1], C[0][2] + 2.f * C[1][2],
       C[0][3] + 2.f * C[1][3], C[0][4] + 2.f * C[1][4]);
#pragma unroll 3
  for (int x = 2; x < kW; ++x) {
    colsum(x, C[x % 3]);
    emit(x - 1, C[0][0] + C[1][0] + C[2][0], C[0][1] + C[1][1] + C[2][1],
         C[0][2] + C[1][2] + C[2][2], C[0][3] + C[1][3] + C[2][3],
         C[0][4] + C[1][4] + C[2][4]);
  }
  emit(kW - 1, C[0][0] + 2.f * C[2][0], C[0][1] + 2.f * C[2][1], C[0][2] + 2.f * C[2][2],
       C[0][3] + 2.f * C[2][3], C[0][4] + 2.f * C[2][4]);
}

// ---------------- kernel 5: argmin over bins -> lowest_cost ----------------
__global__ __launch_bounds__(256) void k_argmin(const float* __restrict__ ssim,
                                                float* __restrict__ lc) {
  int pix = blockIdx.x * 256 + threadIdx.x;  // 7680 exact
  float best = ssim[pix];
  int bi = 0;
  for (int b = 1; b < kNB; b++) {
    float v = ssim[b * kP + pix];
    if (v < best) { best = v; bi = b; }
  }
  float depth = expf(-0.69314718f + (5.2983174f * (float)bi) / 63.0f);
  lc[pix] = 1.f / depth;
}

// ---------------- kernel 6: fused 6-layer transformer ----------------
// R6 = R4 structure (4 waves/block, F2-sA + F2-sB in registers, block-shared
// global_load_lds weight chunks) with the barrier drains removed: 8-slot ring,
// prefetch distance 6, counted `s_waitcnt vmcnt(12)` + raw s_barrier per chunk
// (never vmcnt(0) in the loop). One vmcnt(0) drain before kernel exit (LDS DMA
// must not outlive the workgroup).

constexpr int NW = 4;  // waves (pixels) per block

__device__ __forceinline__ void ln_store(int l, f2v X, unsigned* xhq) {
  float s = X.x + X.y, s2 = X.x * X.x + X.y * X.y;
#pragma unroll
  for (int o = 32; o > 0; o >>= 1) { s += __shfl_xor(s, o); s2 += __shfl_xor(s2, o); }
  float m = s * 0.0078125f;
  float var = s2 * 0.0078125f - m * m;
  float rs = rsqrtf(var + 1e-5f);
  xhq[l] = pkrtz((X.x - m) * rs, (X.y - m) * rs);
}

__device__ __forceinline__ void dot16(uint4 inA, uint4 inB, uint4 wa, uint4 wc,
                                      uint4 wa2, uint4 wc2,
                                      float& a0, float& a1, float& c0, float& c1) {
  a0 = fdot2(inA.x, wa.x, a0);  a0 = fdot2(inA.y, wa.y, a0);
  a0 = fdot2(inA.z, wa.z, a0);  a0 = fdot2(inA.w, wa.w, a0);
  a1 = fdot2(inA.x, wc.x, a1);  a1 = fdot2(inA.y, wc.y, a1);
  a1 = fdot2(inA.z, wc.z, a1);  a1 = fdot2(inA.w, wc.w, a1);
  c0 = fdot2(inB.x, wa2.x, c0); c0 = fdot2(inB.y, wa2.y, c0);
  c0 = fdot2(inB.z, wa2.z, c0); c0 = fdot2(inB.w, wa2.w, c0);
  c1 = fdot2(inB.x, wc2.x, c1); c1 = fdot2(inB.y, wc2.y, c1);
  c1 = fdot2(inB.z, wc2.z, c1); c1 = fdot2(inB.w, wc2.w, c1);
}

// one 8 KB chunk of a std gemm (4 j-chunks), input = 16 u32 broadcast from inb
__device__ __forceinline__ void gemm_chunk(const unsigned* inb, const unsigned* wbp, int l,
                                           float& a0, float& a1, float& c0, float& c1) {
#pragma unroll
  for (int jj = 0; jj < 4; jj += 2) {
    uint4 inA = *(const uint4*)(inb + 4 * jj);
    uint4 inB = *(const uint4*)(inb + 4 * jj + 4);
    const unsigned* w0 = wbp + jj * 512 + l * 4;
    uint4 wa = *(const uint4*)(w0);
    uint4 wc = *(const uint4*)(w0 + 256);
    uint4 wa2 = *(const uint4*)(w0 + 512);
    uint4 wc2 = *(const uint4*)(w0 + 768);
    dot16(inA, inB, wa, wc, wa2, wc2, a0, a1, c0, c1);
  }
}

__global__ __launch_bounds__(256, 2) void k_attn(const unsigned* __restrict__ F2h,
                                                 const unsigned* __restrict__ F2hT,
                                                 const float* __restrict__ f1t,
                                                 const float* __restrict__ wts,
                                                 const float* __restrict__ cab_out,
                                                 float* __restrict__ attn_out) {
  // per-wave: upb (u / p_hi+p_lo / wbar / rawh, 512 u32) + xhq (64 u32)
  __shared__ __align__(16) unsigned shw[NW * 576];
  // 8-slot weight chunk ring (64 KB)
  __shared__ __align__(16) unsigned wbuf[8 * 2048];

  const int tid = threadIdx.x;
  const int w = tid >> 6, l = tid & 63;
  const int pix = blockIdx.x * NW + w;
  unsigned* upb = shw + w * 576;
  unsigned* xhq = upb + 512;
  float* pf = (float*)upb;
  const unsigned* W32all = (const unsigned*)wts;

  const int mrow = l & 31;   // bin row within tile (also MFMA C col = head for n<8)
  const int kg = l >> 5;     // MFMA k-group
  const int rbase = 4 * kg;  // MFMA C row base

  f2v X;
  { float2 xv = ((const float2*)(f1t + (long long)pix * kC))[l]; X.x = xv.x; X.y = xv.y; }

  // ---- prologue: F2 scores-layout -> registers (A-frag per lane) ----
  h8 sA0[8], sA1[8];
  {
    const unsigned* F2a = F2h + (unsigned)pix * 4096u + mrow * 64 + kg * 4;
#pragma unroll
    for (int kc = 0; kc < 8; ++kc) {
      sA0[kc] = *(const h8*)(F2a + kc * 8);
      sA1[kc] = *(const h8*)(F2a + 32 * 64 + kc * 8);
    }
  }
  // ---- prologue: F2 wbar-layout -> registers ----
  h8 sB[16];  // [ct*4+ks]: lane: c = ct*32+(l&31); bins ks*16+kg*8+0..7
  {
    const unsigned* Tb = F2hT + (unsigned)pix * 4096u + (l & 31);
#pragma unroll
    for (int ct = 0; ct < 4; ++ct) {
#pragma unroll
      for (int ks = 0; ks < 4; ++ks) {
        union { unsigned u[4]; h8 h; } t;
#pragma unroll
        for (int j = 0; j < 4; ++j) t.u[j] = Tb[(ks * 8 + kg * 4 + j) * 128 + ct * 32];
        sB[ct * 4 + ks] = t.h;
      }
    }
  }

  // ---- ring prologue: stage chunks 0..5 ----
#pragma unroll
  for (int g = 0; g < 6; ++g) stage_g(W32all, g, wbuf, w, l);
  int gs = 6;  // next chunk to stage

  float chsum = 0.f;
  for (int ly = 0; ly < kNL; ++ly) {
    const float* WL = wts + (long long)ly * WTS_STRIDE;
    const int gb = ly * 20;
    const bool last = (ly == kNL - 1);

    // ---- LN(SA) -> xhq ; SA gemm (chunks gb+0..3) ; residual ----
    ln_store(l, X, xhq);
    wb();
    {
      float2 bv = ((const float2*)(WL + BSA))[l];
      float a0 = bv.x, a1 = bv.y, c0 = 0.f, c1 = 0.f;
#pragma unroll
      for (int k = 0; k < 4; ++k) {
        stage_g(W32all, gs++, wbuf, w, l);
        chunk_wait();
        gemm_chunk(xhq + 16 * k, wbuf + ((gb + k) & 7) * 2048, l, a0, a1, c0, c1);
      }
      X.x += a0 + c0; X.y += a1 + c1;
    }
    // ---- LN(CA) -> xhq ; Q gemm (chunks gb+4..7) ----
    ln_store(l, X, xhq);
    wb();
    f2v q;
    {
      float2 bv = ((const float2*)(WL + BQ))[l];
      float a0 = bv.x, a1 = bv.y, c0 = 0.f, c1 = 0.f;
#pragma unroll
      for (int k = 4; k < 8; ++k) {
        stage_g(W32all, gs++, wbuf, w, l);
        chunk_wait();
        gemm_chunk(xhq + 16 * (k - 4), wbuf + ((gb + k) & 7) * 2048, l, a0, a1, c0, c1);
      }
      q.x = a0 + c0; q.y = a1 + c1;
    }
    if (last) {  // k-bias contribution to raw: full dot q.bk
      float2 bk = ((const float2*)(WL + BK))[l];
      float cp = q.x * bk.x + q.y * bk.y;
#pragma unroll
      for (int o = 32; o > 0; o >>= 1) cp += __shfl_xor(cp, o);
      chsum = cp;
    }
    xhq[l] = pkrtz(q.x, q.y);  // qpk (d-pairs == o-pairs)
    wb();

    // ---- U (chunks gb+8..11, 2 heads/chunk): u[h][c-pair l], store col ^ 4h ----
#pragma unroll
    for (int kk = 0; kk < 4; ++kk) {
      stage_g(W32all, gs++, wbuf, w, l);
      chunk_wait();
      const unsigned* wbp = wbuf + ((gb + 8 + kk) & 7) * 2048;
#pragma unroll
      for (int hh = 0; hh < 2; ++hh) {
        const int h = kk * 2 + hh;
        uint4 q0 = *(const uint4*)(xhq + h * 8);      // o-pairs 0..3 (broadcast)
        uint4 q1 = *(const uint4*)(xhq + h * 8 + 4);  // o-pairs 4..7
        const unsigned* w0 = wbp + hh * 1024 + l * 4;
        uint4 av0 = *(const uint4*)(w0);
        uint4 av1 = *(const uint4*)(w0 + 256);
        uint4 bv0 = *(const uint4*)(w0 + 512);
        uint4 bv1 = *(const uint4*)(w0 + 768);
        float u0 = 0.f, u1 = 0.f, u2 = 0.f, u3 = 0.f;
        u0 = fdot2(q0.x, av0.x, u0); u0 = fdot2(q0.y, av0.y, u0);
        u0 = fdot2(q0.z, av0.z, u0); u0 = fdot2(q0.w, av0.w, u0);
        u2 = fdot2(q1.x, av1.x, u2); u2 = fdot2(q1.y, av1.y, u2);
        u2 = fdot2(q1.z, av1.z, u2); u2 = fdot2(q1.w, av1.w, u2);
        u1 = fdot2(q0.x, bv0.x, u1); u1 = fdot2(q0.y, bv0.y, u1);
        u1 = fdot2(q0.z, bv0.z, u1); u1 = fdot2(q0.w, bv0.w, u1);
        u3 = fdot2(q1.x, bv1.x, u3); u3 = fdot2(q1.y, bv1.y, u3);
        u3 = fdot2(q1.z, bv1.z, u3); u3 = fdot2(q1.w, bv1.w, u3);
        upb[h * 64 + (l ^ (4 * h))] = pkrtz(u0 + u2, u1 + u3);
      }
    }
    wb();

    // ---- scores via MFMA: C[bin][head] = F2 @ u; A from registers ----
    fx16 acc0 = (fx16)0.f, acc1 = (fx16)0.f;
    {
      const int hn = mrow & 7;          // clamp head for n>=8 lanes (dup cols, ignored)
      const int usw = 4 * hn;           // u row swizzle
#pragma unroll
      for (int kc = 0; kc < 8; ++kc) {
        const int cp = kc * 8 + kg * 4;  // u32 column of channel k0 = kc*16+kg*8
        h8 Bv = *(const h8*)(upb + hn * 64 + (cp ^ usw));
        acc0 = __builtin_amdgcn_mfma_f32_32x32x16_f16(sA0[kc], Bv, acc0, 0, 0, 0);
        acc1 = __builtin_amdgcn_mfma_f32_32x32x16_f16(sA1[kc], Bv, acc1, 0, 0, 0);
      }
    }
    if (last) {
      // raw[bin] = sum_h sc[bin][h] + chsum; redistribute via pf as rawh[8][64]
      wb();
      if (mrow < 8) {
#pragma unroll
        for (int r = 0; r < 16; ++r) {
          int row = (r & 3) + 8 * (r >> 2) + rbase;
          pf[mrow * 64 + row] = acc0[r];
          pf[mrow * 64 + 32 + row] = acc1[r];
        }
      }
      wb();
      float rsum = chsum;
#pragma unroll
      for (int h = 0; h < kNH; ++h) rsum += pf[h * 64 + l];
      attn_out[(long long)pix * 64 + l] = rsum;
      // drain LDS-DMA before workgroup exit (pending gl_lds must not outlive LDS)
      __asm__ __volatile__("s_waitcnt vmcnt(0)" ::: "memory");
      return;
    }
    // ---- softmax over bins: head h lives in lanes {h, h+32} (16+16 rows each) ----
    // p stored to LDS as hi/lo f16 bin-pairs: p_hi [8h][36-padded bpair] at upb+0,
    // p_lo at upb+288 (spills into xhq region — q already consumed).
    {
      float mx = acc0[0];
#pragma unroll
      for (int r = 0; r < 16; ++r) { mx = fmaxf(mx, acc0[r]); mx = fmaxf(mx, acc1[r]); }
      mx = fmaxf(mx, __shfl_xor(mx, 32));
      float pv0[16], pv1[16];
      float sm = 0.f;
#pragma unroll
      for (int r = 0; r < 16; ++r) {
        pv0[r] = __expf(acc0[r] - mx); sm += pv0[r];
        pv1[r] = __expf(acc1[r] - mx); sm += pv1[r];
      }
      sm += __shfl_xor(sm, 32);
      float inv = 1.f / sm;
      wb();  // all u (B-frag) reads complete before p overwrites upb
      if (mrow < 8) {
#pragma unroll
        for (int r = 0; r < 16; r += 2) {
          int row = (r & 3) + 8 * (r >> 2) + rbase;  // bins row, row+1 (row even)
          int bp = row >> 1;
          float x0 = pv0[r] * inv, x1 = pv0[r + 1] * inv;
          unsigned uh = pkrtz(x0, x1); f2v bk = h2f(uh);
          unsigned ul = pkrtz(x0 - bk.x, x1 - bk.y);
          upb[mrow * 36 + bp] = uh;
          upb[288 + mrow * 36 + bp] = ul;
          float y0 = pv1[r] * inv, y1 = pv1[r + 1] * inv;  // bins +32
          unsigned vh = pkrtz(y0, y1); f2v bk2 = h2f(vh);
          unsigned vl = pkrtz(y0 - bk2.x, y1 - bk2.y);
          upb[mrow * 36 + 16 + bp] = vh;
          upb[288 + mrow * 36 + 16 + bp] = vl;
        }
      }
    }
    wb();
    // ---- wbar via MFMA: D[c][h] = sum_b F2[b][c] p[b][h]; A = sB regs ----
    {
      const int hb = mrow & 7;
      h8 ph[4], pl[4];
#pragma unroll
      for (int ks = 0; ks < 4; ++ks) {
        ph[ks] = *(const h8*)(upb + hb * 36 + ks * 8 + kg * 4);
        pl[ks] = *(const h8*)(upb + 288 + hb * 36 + ks * 8 + kg * 4);
      }
      wb();
      const bool wval = mrow < 8;
#pragma unroll
      for (int ct = 0; ct < 4; ++ct) {
        fx16 a = (fx16)0.f;
#pragma unroll
        for (int ks = 0; ks < 4; ++ks) {
          a = __builtin_amdgcn_mfma_f32_32x32x16_f16(sB[ct * 4 + ks], ph[ks], a, 0, 0, 0);
          a = __builtin_amdgcn_mfma_f32_32x32x16_f16(sB[ct * 4 + ks], pl[ks], a, 0, 0, 0);
        }
        if (wval) {
#pragma unroll
          for (int r = 0; r < 16; r += 2) {
            int m = (r & 3) + 8 * (r >> 2) + rbase;  // channel-in-tile (even)
            int cpair = ct * 16 + (m >> 1);
            upb[mrow * 64 + (cpair ^ (4 * mrow))] = pkrtz(a[r], a[r + 1]);
          }
        }
      }
    }
    wb();
    // ---- AO (chunks gb+12..15): ao[d] = wbar[h(d)] . Wv'[:,d] + bv ----
    {
      const int h = l >> 3, sw = 4 * h;  // d=2l -> head
      const unsigned* wrow = upb + h * 64;
      float2 bv = ((const float2*)(WL + BV))[l];
      float a0 = bv.x, a1 = bv.y, c0 = 0.f, c1 = 0.f;
#pragma unroll
      for (int k = 12; k < 16; ++k) {
        stage_g(W32all, gs++, wbuf, w, l);
        chunk_wait();
        const unsigned* wbp = wbuf + ((gb + k) & 7) * 2048;
#pragma unroll
        for (int jj = 0; jj < 4; jj += 2) {
          const int j = (k - 12) * 4 + jj;
          uint4 inA = *(const uint4*)(wrow + ((4 * j) ^ sw));
          uint4 inB = *(const uint4*)(wrow + ((4 * j + 4) ^ sw));
          const unsigned* w0 = wbp + jj * 512 + l * 4;
          uint4 wa = *(const uint4*)(w0);
          uint4 wc = *(const uint4*)(w0 + 256);
          uint4 wa2 = *(const uint4*)(w0 + 512);
          uint4 wc2 = *(const uint4*)(w0 + 768);
          dot16(inA, inB, wa, wc, wa2, wc2, a0, a1, c0, c1);
        }
      }
      xhq[l] = pkrtz(a0 + c0, a1 + c1);
    }
    wb();
    // ---- O (chunks gb+16..19): X += ao @ Wo^T + bo ----
    {
      float2 bv = ((const float2*)(cab_out + ly * kC))[l];
      float a0 = bv.x, a1 = bv.y, c0 = 0.f, c1 = 0.f;
#pragma unroll
      for (int k = 16; k < 20; ++k) {
        stage_g(W32all, gs++, wbuf, w, l);
        chunk_wait();
        gemm_chunk(xhq + 16 * (k - 16), wbuf + ((gb + k) & 7) * 2048, l, a0, a1, c0, c1);
      }
      X.x += a0 + c0; X.y += a1 + c1;
    }
    wb();
  }
}

// ---------------- launch ----------------
extern "C" void kernel_launch(void* const* d_in, const int* in_sizes, int n_in, void* d_out,
                              int out_size, void* d_ws, size_t ws_size, hipStream_t stream) {
  (void)in_sizes; (void)n_in; (void)out_size; (void)ws_size;
  const float* feat1 = (const float*)d_in[0];
  const float* feat2 = (const float*)d_in[1];
  const float* coords = (const float*)d_in[2];
  const float* sa_in_w = (const float*)d_in[3];
  const float* sa_in_b = (const float*)d_in[4];
  const float* sa_out_w = (const float*)d_in[5];
  const float* sa_out_b = (const float*)d_in[6];
  const float* sa_ln_g = (const float*)d_in[7];
  const float* sa_ln_b = (const float*)d_in[8];
  const float* ca_in_w = (const float*)d_in[9];
  const float* ca_in_b = (const float*)d_in[10];
  const float* ca_out_w = (const float*)d_in[11];
  const float* ca_out_b = (const float*)d_in[12];
  const float* ca_ln_g = (const float*)d_in[13];
  const float* ca_ln_b = (const float*)d_in[14];

  float* out = (float*)d_out;
  float* ws = (float*)d_ws;
  float* f1t = ws + OFF_F1T;
  float* f2t = ws + OFF_F2T;
  float* wts = ws + OFF_WTS;
  unsigned* F2h = (unsigned*)(ws + OFF_F2H);
  unsigned* F2hT = (unsigned*)(ws + OFF_F2HT);

  float* att = out + OUT_ATT;
  float* mask = out + OUT_MASK;
  float* lc = out + OUT_LC;
  float* ssim = out + OUT_SSIM;

  dim3 gt(240, 4);
  k_transpose<<<gt, 256, 0, stream>>>(feat1, feat2, f1t, f2t);
  k_fold<<<kNL * 128, 128, 0, stream>>>(sa_in_w, sa_in_b, sa_out_w, sa_out_b, sa_ln_g, sa_ln_b,
                                        ca_in_w, ca_in_b, ca_ln_g, ca_ln_b, ca_out_w, wts);
  dim3 g1(1920, 32);
  k_warp<<<g1, 256, 0, stream>>>(f2t, coords, F2h, F2hT, mask);
  dim3 g2(12, 64);
  k_ssim<<<g2, 256, 0, stream>>>(f1t, f2t, coords, ssim);
  k_argmin<<<30, 256, 0, stream>>>(ssim, lc);
  k_attn<<<kP / NW, 64 * NW, 0, stream>>>(F2h, F2hT, f1t, wts, ca_out_b, att);
}